// Round 13
// baseline (307.483 us; speedup 1.0000x reference)
//
#include <hip/hip_runtime.h>

#define B_   4
#define CIN  23
#define H_   256
#define W_   512
#define CO   64
#define HC   8                   // h-chunks of 32
#define NPART (B_ * W_ * CO)     // 131072 floats per h-chunk partial

typedef float f32x4 __attribute__((ext_vector_type(4)));
typedef _Float16 half8 __attribute__((ext_vector_type(8)));

// ---------------------------------------------------------------------------
// INSTRUMENTATION ROUND v2: exact round-7/8 known-good kernels, but with
// DUPLICATED GRIDS (conv x8, pairs x4). All duplicate blocks write identical
// bytes to identical addresses -> final memory identical, correctness exact.
// Purpose: push our dispatch durations above the ~150-170us harness fills so
// the top-5 rocprof rows show OUR kernels' true counters and the conv/pairs
// time split. Next round reverts duplication.
// ---------------------------------------------------------------------------

// Kernel A: conv(23->64)+bias+relu, partial h-sum via MFMA (16x16x32 f16).
// (round-7 structure; xs pad now zero-initialized -> fully deterministic)
__global__ __launch_bounds__(256) void conv_mfma_kernel(
    const float* __restrict__ msa,   // [B][CIN][H][W]
    const float* __restrict__ Wc,    // [CO][CIN]
    const float* __restrict__ bias,  // [CO]
    float* __restrict__ partial)     // [HC][B][W][CO]
{
    const int tid  = threadIdx.x;
    const int lane = tid & 63;
    const int mg   = tid >> 6;        // wave id = co-group 0..3
    const int wrow = lane & 15;
    const int kg   = lane >> 4;       // 0..3

    const int wq = blockIdx.x;        // 0..31
    const int hc = blockIdx.y;        // 0..7
    const int b  = blockIdx.z & 3;    // 8 duplicate copies along z
    const int w0 = wq * 16;

    half8 afrag;
#pragma unroll
    for (int j = 0; j < 8; ++j) {
        const int k = 8 * kg + j;
        afrag[j] = (_Float16)((k < CIN) ? Wc[(16 * mg + wrow) * CIN + k] : 0.f);
    }
    float bias_r[4];
#pragma unroll
    for (int r = 0; r < 4; ++r) bias_r[r] = bias[16 * mg + 4 * kg + r];

    float acc0 = 0.f, acc1 = 0.f, acc2 = 0.f, acc3 = 0.f;

    __shared__ __align__(16) _Float16 xs[4][16][40];
    // zero-init (esp. the k=23..31 pad that MFMA reads against zero weights)
    for (int t = lane; t < 16 * 40; t += 64)
        (&xs[mg][0][0])[t] = (_Float16)0.f;
    __syncthreads();

    const size_t HW = (size_t)H_ * W_;

    for (int step = 0; step < 8; ++step) {
        const int hg = hc * 32 + step * 4 + mg;
        {
            const float* src = msa + ((size_t)b * CIN) * HW + (size_t)hg * W_ + w0 + wrow;
#pragma unroll
            for (int m = 0; m < 6; ++m) {
                const int i = kg + 4 * m;        // covers 0..22 once
                if (i < CIN)
                    xs[mg][wrow][i] = (_Float16)src[(size_t)i * HW];
            }
        }
        __syncthreads();
#pragma unroll
        for (int hh = 0; hh < 4; ++hh) {
            const half8 bfrag = *(const half8*)&xs[hh][wrow][8 * kg];
            f32x4 c = {0.f, 0.f, 0.f, 0.f};
            c = __builtin_amdgcn_mfma_f32_16x16x32_f16(afrag, bfrag, c, 0, 0, 0);
            acc0 += fmaxf(c[0] + bias_r[0], 0.f);
            acc1 += fmaxf(c[1] + bias_r[1], 0.f);
            acc2 += fmaxf(c[2] + bias_r[2], 0.f);
            acc3 += fmaxf(c[3] + bias_r[3], 0.f);
        }
        __syncthreads();
    }

    f32x4 v; v[0] = acc0; v[1] = acc1; v[2] = acc2; v[3] = acc3;
    float* dst = partial + (((size_t)hc * B_ + b) * W_ + w0 + wrow) * CO + 16 * mg + 4 * kg;
    *(f32x4*)dst = v;
}

// Kernel B: avg = (1/H) * sum_hc partial   (float4-wide)
__global__ __launch_bounds__(256) void reduce_avg_kernel(
    const float* __restrict__ partial,  // [HC][B][W][CO]
    float* __restrict__ avg)            // [B][W][CO]
{
    const int idx = blockIdx.x * 256 + threadIdx.x;   // f32x4 index
    const f32x4* p4 = (const f32x4*)partial;
    f32x4 s = p4[idx];
#pragma unroll
    for (int k = 1; k < HC; ++k) s += p4[(size_t)k * (NPART / 4) + idx];
    ((f32x4*)avg)[idx] = s * (1.0f / H_);
}

// Kernel C: out[b][wi][wj][c] = avg[b][wi][c] + avg[b][wj][c]  (NT stores)
__global__ __launch_bounds__(256) void pairs_kernel(
    const float* __restrict__ avg,  // [B][W][CO]
    float* __restrict__ out)        // [B][W][W][CO]
{
    const int b   = blockIdx.y & 3;   // 4 duplicate copies along y
    const int wi  = blockIdx.x;
    const int tid = threadIdx.x;
    const int cq  = tid & 15;
    const int wj0 = tid >> 4;

    const f32x4* a4 = (const f32x4*)avg;
    const f32x4 aI = a4[(b * W_ + wi) * 16 + cq];
    f32x4* o4 = (f32x4*)out + ((size_t)(b * W_ + wi)) * W_ * 16;

#pragma unroll 4
    for (int wj = wj0; wj < W_; wj += 16) {
        const f32x4 aJ = a4[(b * W_ + wj) * 16 + cq];
        const f32x4 r = aI + aJ;
        __builtin_nontemporal_store(r, o4 + (size_t)wj * 16 + cq);
    }
}

extern "C" void kernel_launch(void* const* d_in, const int* in_sizes, int n_in,
                              void* d_out, int out_size, void* d_ws, size_t ws_size,
                              hipStream_t stream) {
    const float* msa = (const float*)d_in[0];   // (4, 23, 256, 512)
    const float* Wc  = (const float*)d_in[1];   // (64, 23)
    const float* bc  = (const float*)d_in[2];   // (64,)
    float* out = (float*)d_out;                 // (4, 512, 512, 64)
    float* avg = (float*)d_ws;                  // (4, 512, 64) = 512 KB scratch

    // partial[8][4][512][64] = 4 MiB staged in d_out; overwritten by pairs.
    float* partial = (float*)d_out;

    conv_mfma_kernel<<<dim3(32, HC, B_ * 8), 256, 0, stream>>>(msa, Wc, bc, partial);
    reduce_avg_kernel<<<dim3(NPART / 4 / 256), 256, 0, stream>>>(partial, avg);
    pairs_kernel<<<dim3(W_, B_ * 4), 256, 0, stream>>>(avg, out);
}

// Round 14
// 69.258 us; speedup vs baseline: 4.4397x; 4.4397x over previous
//
#include <hip/hip_runtime.h>

#define B_   4
#define CIN  23
#define H_   256
#define W_   512
#define CO   64
#define HC   8                   // h-chunks of 32
#define NPART (B_ * W_ * CO)     // 131072 floats per h-chunk partial

typedef float f32x4 __attribute__((ext_vector_type(4)));
typedef _Float16 half8 __attribute__((ext_vector_type(8)));

// ---------------------------------------------------------------------------
// Kernel A: conv(23->64)+bias+relu, partial h-sum via MFMA (16x16x32 f16).
// Grid (wq=32, hc=8, b=4) = 1024 blocks x 256 thr (4 waves, 4 blocks/CU).
// Block tile: 16 w x 32 h x all 64 co; wave mg = co-group [16mg,16mg+16).
// DOUBLE-BUFFERED LDS staging: step s+1's global loads issue before step s's
// compute, ONE __syncthreads per step (8 total, was 16).
// Frag layout (verified R8/R10): A lane=(m=l&15, k=8*(l>>4)+j), B lane=
// (n=l&15, k=8*(l>>4)+j), C lane=(m=4*(l>>4)+r, n=l&15).
// ---------------------------------------------------------------------------
__global__ __launch_bounds__(256) void conv_mfma_kernel(
    const float* __restrict__ msa,   // [B][CIN][H][W]
    const float* __restrict__ Wc,    // [CO][CIN]
    const float* __restrict__ bias,  // [CO]
    float* __restrict__ partial)     // [HC][B][W][CO]
{
    const int tid  = threadIdx.x;
    const int lane = tid & 63;
    const int mg   = tid >> 6;        // wave id = co-group 0..3 (also h-slot for staging)
    const int wrow = lane & 15;
    const int kg   = lane >> 4;       // 0..3

    const int wq = blockIdx.x;        // 0..31
    const int hc = blockIdx.y;        // 0..7
    const int b  = blockIdx.z;
    const int w0 = wq * 16;

    // A fragment: W[16mg + wrow][8kg + j], zero-padded k>=23
    half8 afrag;
#pragma unroll
    for (int j = 0; j < 8; ++j) {
        const int k = 8 * kg + j;
        afrag[j] = (_Float16)((k < CIN) ? Wc[(16 * mg + wrow) * CIN + k] : 0.f);
    }
    float bias_r[4];
#pragma unroll
    for (int r = 0; r < 4; ++r) bias_r[r] = bias[16 * mg + 4 * kg + r];

    float acc0 = 0.f, acc1 = 0.f, acc2 = 0.f, acc3 = 0.f;

    // [buf][h-slot][w][k] ; row stride 40 halfs = 80B; 10 KiB total
    __shared__ __align__(16) _Float16 xs[2][4][16][40];
    // zero-init once (esp. the k=23..39 pad read by MFMA against zero weights)
    for (int t = tid; t < 2 * 4 * 16 * 40; t += 256)
        (&xs[0][0][0][0])[t] = (_Float16)0.f;

    const size_t HW = (size_t)H_ * W_;

    // stage h-slot mg of step s into buffer bufi (all 64 lanes: lane=(wrow,kg))
    auto STAGE = [&](int s, int bufi) {
        const int hg = hc * 32 + s * 4 + mg;
        const float* src = msa + ((size_t)b * CIN) * HW + (size_t)hg * W_ + w0 + wrow;
#pragma unroll
        for (int m = 0; m < 6; ++m) {
            const int i = kg + 4 * m;        // covers 0..22 once across (kg,m)
            if (i < CIN)
                xs[bufi][mg][wrow][i] = (_Float16)src[(size_t)i * HW];
        }
    };

    STAGE(0, 0);
    __syncthreads();

#pragma unroll 2
    for (int s = 0; s < 8; ++s) {
        const int cur = s & 1;
        if (s < 7) STAGE(s + 1, cur ^ 1);   // loads fly under compute below
#pragma unroll
        for (int hh = 0; hh < 4; ++hh) {
            const half8 bfrag = *(const half8*)&xs[cur][hh][wrow][8 * kg];
            f32x4 c = {0.f, 0.f, 0.f, 0.f};
            c = __builtin_amdgcn_mfma_f32_16x16x32_f16(afrag, bfrag, c, 0, 0, 0);
            acc0 += fmaxf(c[0] + bias_r[0], 0.f);
            acc1 += fmaxf(c[1] + bias_r[1], 0.f);
            acc2 += fmaxf(c[2] + bias_r[2], 0.f);
            acc3 += fmaxf(c[3] + bias_r[3], 0.f);
        }
        __syncthreads();
    }

    f32x4 v; v[0] = acc0; v[1] = acc1; v[2] = acc2; v[3] = acc3;
    float* dst = partial + (((size_t)hc * B_ + b) * W_ + w0 + wrow) * CO + 16 * mg + 4 * kg;
    *(f32x4*)dst = v;
}

// ---------------------------------------------------------------------------
// Kernel B: avg[b][w][c] = (1/H) * sum_hc partial[hc][b][w][c]   (float4-wide)
// ---------------------------------------------------------------------------
__global__ __launch_bounds__(256) void reduce_avg_kernel(
    const float* __restrict__ partial,  // [HC][B][W][CO]
    float* __restrict__ avg)            // [B][W][CO]
{
    const int idx = blockIdx.x * 256 + threadIdx.x;   // f32x4 index
    const f32x4* p4 = (const f32x4*)partial;
    f32x4 s = p4[idx];
#pragma unroll
    for (int k = 1; k < HC; ++k) s += p4[(size_t)k * (NPART / 4) + idx];
    ((f32x4*)avg)[idx] = s * (1.0f / H_);
}

// ---------------------------------------------------------------------------
// Kernel C: out[b][wi][wj][c] = avg[b][wi][c] + avg[b][wj][c]
// PLAIN stores (harness fills reach 6.9-7.0 TB/s with plain dwordx4;
// NT measured 5.2 TB/s). Grid (wi=512, b=4) x 256 thr.
// ---------------------------------------------------------------------------
__global__ __launch_bounds__(256) void pairs_kernel(
    const float* __restrict__ avg,  // [B][W][CO]
    float* __restrict__ out)        // [B][W][W][CO]
{
    const int b   = blockIdx.y;
    const int wi  = blockIdx.x;
    const int tid = threadIdx.x;
    const int cq  = tid & 15;   // c-quad (64 c = 16 float4)
    const int wj0 = tid >> 4;   // 0..15

    const f32x4* a4 = (const f32x4*)avg;
    const f32x4 aI = a4[(b * W_ + wi) * 16 + cq];
    f32x4* o4 = (f32x4*)out + ((size_t)(b * W_ + wi)) * W_ * 16;

#pragma unroll 4
    for (int wj = wj0; wj < W_; wj += 16) {
        const f32x4 aJ = a4[(b * W_ + wj) * 16 + cq];
        o4[(size_t)wj * 16 + cq] = aI + aJ;
    }
}

extern "C" void kernel_launch(void* const* d_in, const int* in_sizes, int n_in,
                              void* d_out, int out_size, void* d_ws, size_t ws_size,
                              hipStream_t stream) {
    const float* msa = (const float*)d_in[0];   // (4, 23, 256, 512)
    const float* Wc  = (const float*)d_in[1];   // (64, 23)
    const float* bc  = (const float*)d_in[2];   // (64,)
    float* out = (float*)d_out;                 // (4, 512, 512, 64)
    float* avg = (float*)d_ws;                  // (4, 512, 64) = 512 KB scratch

    // partial[8][4][512][64] = 4 MiB staged in d_out; overwritten by pairs.
    float* partial = (float*)d_out;

    conv_mfma_kernel<<<dim3(32, HC, B_), 256, 0, stream>>>(msa, Wc, bc, partial);
    reduce_avg_kernel<<<dim3(NPART / 4 / 256), 256, 0, stream>>>(partial, avg);
    pairs_kernel<<<dim3(W_, B_), 256, 0, stream>>>(avg, out);
}